// Round 2
// baseline (797.597 us; speedup 1.0000x reference)
//
#include <hip/hip_runtime.h>
#include <cstdint>
#include <cstddef>

typedef unsigned short u16;
typedef __attribute__((ext_vector_type(8))) short short8;   // 8 x bf16 MFMA A/B frag
typedef __attribute__((ext_vector_type(4))) short short4v;
typedef __attribute__((ext_vector_type(4))) float f32x4;    // MFMA C/D frag

#define NTOK 65536
#define HID 512
#define NVOCAB 1024
#define HSTRIDE 520   // 128-token h tile leading dim (pad: 260 words -> 4-bank row offset)

// ---------- bf16 helpers (raw-bit, RNE) ----------
__device__ __forceinline__ u16 f2bf(float f) {
  union { float f; uint32_t u; } v; v.f = f;
  uint32_t r = (v.u + 0x7FFFu + ((v.u >> 16) & 1u)) >> 16;
  return (u16)r;
}
__device__ __forceinline__ float bf2f(u16 b) {
  union { uint32_t u; float f; } v; v.u = ((uint32_t)b) << 16;
  return v.f;
}

// async global->LDS, 16B per lane; LDS dest = wave-uniform base + lane*16
__device__ __forceinline__ void gl_lds16(const u16* g, u16* l) {
  __builtin_amdgcn_global_load_lds(
      (const __attribute__((address_space(1))) uint32_t*)g,
      (__attribute__((address_space(3))) uint32_t*)l, 16, 0, 0);
}

// ---------- hash constants ----------
__constant__ uint32_t P24[24] = {
  2654435761u, 2246822519u, 3266489917u, 2028178513u, 1220703125u,
  1610612741u, 805306457u, 402653189u, 3674653429u, 2860486313u,
  1073676287u, 2971215073u, 1500450271u, 3267000013u, 2654435789u,
  4049292737u, 2246822531u, 3266489927u, 2028178519u, 1220703133u,
  1610612743u, 805306459u, 402653191u, 3674653433u};
__constant__ unsigned char OFFS[32][3] = {
  {1,0,0},{2,0,0},{3,0,0},{4,0,0},{5,0,0},{6,0,0},{7,0,0},{8,0,0},
  {1,2,0},{2,3,0},{3,4,0},{1,3,0},{2,4,0},{1,4,0},{1,5,0},{2,5,0},
  {3,5,0},{1,6,0},{2,6,0},{1,7,0},
  {1,2,3},{1,2,4},{1,3,5},{2,3,4},{1,2,5},{1,3,4},{2,4,6},{1,4,7},
  {1,8,0},{1,9,0},{1,10,0},{1,11,0}};
__constant__ unsigned char PLEN[32] = {
  1,1,1,1,1,1,1,1, 2,2,2,2,2,2,2,2,2,2,2,2, 3,3,3,3,3,3,3,3, 2,2,2,2};

// ---------- weight fp32 -> bf16 ----------
__global__ __launch_bounds__(256) void cvt_bf16(const float* __restrict__ src,
                                                u16* __restrict__ dst, int n) {
  int i = (blockIdx.x * 256 + threadIdx.x) * 4;
  if (i < n) {
    float4 f = *(const float4*)(src + i);
    short4v o;
    o[0] = (short)f2bf(f.x); o[1] = (short)f2bf(f.y);
    o[2] = (short)f2bf(f.z); o[3] = (short)f2bf(f.w);
    *(short4v*)(dst + i) = o;
  }
}

// stage one W chunk [128 rows x 32 k] (rows nt*128.., k k0..k0+32) into 8KB LDS buf.
// wave handles 32 rows (2 x 16-row chunks); K is always 512.
__device__ __forceinline__ void stageW(const u16* __restrict__ W, int nt, int k0,
                                       u16* dst, int wave, int lane) {
  const int c0 = wave << 1;
  const int rr = lane >> 2;
  const int cc = (lane & 3) << 3;
  const u16* g = W + (((size_t)((nt << 7) + (c0 << 4) + rr)) << 9) + k0 + cc;
  gl_lds16(g,              dst + ((size_t)c0 << 9));
  gl_lds16(g + (16 << 9),  dst + ((size_t)(c0 + 1) << 9));
}

__device__ __forceinline__ const u16* layer_w(int l, const u16* wInB,
                                              const u16* wMlpB, const u16* wOutB) {
  if (l == 0) return wInB;
  if (l < 4) return wMlpB + ((size_t)(l - 1) << 18);
  return wOutB;
}

// ---------- the fused model: feat + 4x(512x512) + 1024x512, per 128-token tile ----------
__global__ __launch_bounds__(256, 1) void fused_model(
    const int* __restrict__ chars, const float* __restrict__ byte_embed,
    const float* __restrict__ hash_tables,
    const float* __restrict__ b_in, const float* __restrict__ mlp_bs,
    const float* __restrict__ b_out,
    const u16* __restrict__ wInB, const u16* __restrict__ wMlpB,
    const u16* __restrict__ wOutB, float* __restrict__ out)
{
  extern __shared__ u16 smem[];
  u16* hBuf  = smem;                        // 128 x HSTRIDE bf16 = 133,120 B
  u16* wBufA = smem + 128 * HSTRIDE;        // 8 KB
  u16* wBufB = wBufA + 4096;                // 8 KB

  const int tid  = threadIdx.x;
  const int wave = tid >> 6;
  const int lane = tid & 63;
  const int T0   = blockIdx.x << 7;

  // kick off weight-stage pipeline: stage 0 = (layer0, nt0, k0) -> wBufA
  stageW(wInB, 0, 0, wBufA, wave, lane);

  // ---------- feature phase -> hBuf ----------
  {
    const int seg = lane;       // 0..31: byte-embed seg; 32..63: hash table seg-32
    for (int g = 0; g < 32; ++g) {
      const int tokL = (g << 2) + wave;
      const size_t t = (size_t)(T0 + tokL);
      const int s = (int)(t & 2047);
      if (seg < 32) {
        const int c = chars[t];
        const float* src = byte_embed + ((size_t)c << 8) + (seg << 3);
        float4 f0 = ((const float4*)src)[0];
        float4 f1 = ((const float4*)src)[1];
        short8 o;
        o[0]=(short)f2bf(f0.x); o[1]=(short)f2bf(f0.y); o[2]=(short)f2bf(f0.z); o[3]=(short)f2bf(f0.w);
        o[4]=(short)f2bf(f1.x); o[5]=(short)f2bf(f1.y); o[6]=(short)f2bf(f1.z); o[7]=(short)f2bf(f1.w);
        *(short8*)&hBuf[tokL * HSTRIDE + (seg << 3)] = o;
      } else {
        const int i = seg - 32;
        const int pl = (int)PLEN[i];
        long long h = 0;
        #pragma unroll
        for (int k = 0; k < 3; ++k) {
          if (k < pl) {
            const int off = (int)OFFS[i][k];
            const long long tok = (s >= off) ? (long long)chars[t - off] : 0ll;
            h ^= tok * (long long)P24[(3 * i + k) % 24];
          }
        }
        const int idx_lo = (int)(h & 4095);
        const long long sp = (long long)P24[(3 * i + pl) % 24];
        const long long prod = (long long)((unsigned long long)h * (unsigned long long)sp);
        const long long h2 = h ^ (prod >> 16);
        const int idx_hi = (int)(h2 & 4095);
        const float frac = ((float)(int)((h >> 3) & 255) / 255.0f) * 0.4f;
        const float om = 1.0f - frac;
        const float* plo = hash_tables + (((size_t)i << 12) + (size_t)idx_lo) * 8;
        const float* phi = hash_tables + (((size_t)i << 12) + (size_t)idx_hi) * 8;
        float4 a0 = ((const float4*)plo)[0], a1 = ((const float4*)plo)[1];
        float4 b0 = ((const float4*)phi)[0], b1 = ((const float4*)phi)[1];
        short8 o;
        o[0]=(short)f2bf(a0.x*om + b0.x*frac); o[1]=(short)f2bf(a0.y*om + b0.y*frac);
        o[2]=(short)f2bf(a0.z*om + b0.z*frac); o[3]=(short)f2bf(a0.w*om + b0.w*frac);
        o[4]=(short)f2bf(a1.x*om + b1.x*frac); o[5]=(short)f2bf(a1.y*om + b1.y*frac);
        o[6]=(short)f2bf(a1.z*om + b1.z*frac); o[7]=(short)f2bf(a1.w*om + b1.w*frac);
        *(short8*)&hBuf[tokL * HSTRIDE + 256 + (i << 3)] = o;
      }
    }
  }

  const int wr = wave >> 1, wc = wave & 1;   // 2x2 wave grid over [128 tok x 128 col] chunk
  const int mrow = lane & 15;
  const int kg = (lane >> 4) << 3;
  const int lm = (lane >> 4) << 2;
  const int ln = lane & 15;
  int buf = 0;

  // ---------- layers 0..3 (512x512, relu, resid for l>0) ----------
  for (int l = 0; l < 4; ++l) {
    const u16* WL = layer_w(l, wInB, wMlpB, wOutB);
    const float* biasL = (l == 0) ? b_in : (mlp_bs + ((l - 1) << 9));
    uint32_t keep[4][32];
    #pragma unroll
    for (int nt = 0; nt < 4; ++nt) {
      f32x4 acc[4][4];
      #pragma unroll
      for (int x = 0; x < 4; ++x)
        #pragma unroll
        for (int y = 0; y < 4; ++y) acc[x][y] = (f32x4){0.f, 0.f, 0.f, 0.f};

      for (int kk = 0; kk < 16; ++kk) {
        __syncthreads();                       // current stage arrived; prev buf free
        u16* nb = buf ? wBufA : wBufB;
        const u16* cb = buf ? wBufB : wBufA;
        if (kk < 15) {
          stageW(WL, nt, (kk + 1) << 5, nb, wave, lane);
        } else {
          int nt2 = nt + 1, l2 = l;
          if (nt2 == 4) { nt2 = 0; ++l2; }
          stageW(layer_w(l2, wInB, wMlpB, wOutB), nt2, 0, nb, wave, lane);
        }
        const int k0 = kk << 5;
        short8 a[4], b[4];
        #pragma unroll
        for (int i = 0; i < 4; ++i) {
          b[i] = *(const short8*)&cb[(((wc << 6) + (i << 4) + mrow) << 5) + kg];
          a[i] = *(const short8*)&hBuf[((wr << 6) + (i << 4) + mrow) * HSTRIDE + k0 + kg];
        }
        #pragma unroll
        for (int mt = 0; mt < 4; ++mt)
          #pragma unroll
          for (int nti = 0; nti < 4; ++nti)
            acc[mt][nti] = __builtin_amdgcn_mfma_f32_16x16x32_bf16(a[mt], b[nti], acc[mt][nti], 0, 0, 0);
        buf ^= 1;
      }

      // chunk epilogue: bias + relu (+ resid) -> packed bf16 in VGPRs
      #pragma unroll
      for (int nti = 0; nti < 4; ++nti) {
        const int colg = (nt << 7) + (wc << 6) + (nti << 4) + ln;
        const float bs = biasL[colg];
        #pragma unroll
        for (int mt = 0; mt < 4; ++mt) {
          const int rowL = (wr << 6) + (mt << 4) + lm;
          float v[4];
          #pragma unroll
          for (int r = 0; r < 4; ++r) {
            float x = fmaxf(acc[mt][nti][r] + bs, 0.0f);
            if (l > 0) x += bf2f(hBuf[(rowL + r) * HSTRIDE + colg]);
            v[r] = x;
          }
          keep[nt][(nti << 3) + (mt << 1)]     = (uint32_t)f2bf(v[0]) | ((uint32_t)f2bf(v[1]) << 16);
          keep[nt][(nti << 3) + (mt << 1) + 1] = (uint32_t)f2bf(v[2]) | ((uint32_t)f2bf(v[3]) << 16);
        }
      }
    }

    __syncthreads();   // all reads of old h (frags + resid) complete
    #pragma unroll
    for (int nt = 0; nt < 4; ++nt)
      #pragma unroll
      for (int nti = 0; nti < 4; ++nti) {
        const int colg = (nt << 7) + (wc << 6) + (nti << 4) + ln;
        #pragma unroll
        for (int mt = 0; mt < 4; ++mt) {
          const int rowL = (wr << 6) + (mt << 4) + lm;
          const uint32_t p0 = keep[nt][(nti << 3) + (mt << 1)];
          const uint32_t p1 = keep[nt][(nti << 3) + (mt << 1) + 1];
          hBuf[(rowL + 0) * HSTRIDE + colg] = (u16)p0;
          hBuf[(rowL + 1) * HSTRIDE + colg] = (u16)(p0 >> 16);
          hBuf[(rowL + 2) * HSTRIDE + colg] = (u16)p1;
          hBuf[(rowL + 3) * HSTRIDE + colg] = (u16)(p1 >> 16);
        }
      }
    // visibility of new h covered by next k-iter's __syncthreads
  }

  // ---------- layer 4: logits = h @ w_out^T + b_out (fp32 to global) ----------
  for (int nt = 0; nt < 8; ++nt) {
    f32x4 acc[4][4];
    #pragma unroll
    for (int x = 0; x < 4; ++x)
      #pragma unroll
      for (int y = 0; y < 4; ++y) acc[x][y] = (f32x4){0.f, 0.f, 0.f, 0.f};

    for (int kk = 0; kk < 16; ++kk) {
      __syncthreads();
      u16* nb = buf ? wBufA : wBufB;
      const u16* cb = buf ? wBufB : wBufA;
      if (kk < 15)      stageW(wOutB, nt, (kk + 1) << 5, nb, wave, lane);
      else if (nt < 7)  stageW(wOutB, nt + 1, 0, nb, wave, lane);
      const int k0 = kk << 5;
      short8 a[4], b[4];
      #pragma unroll
      for (int i = 0; i < 4; ++i) {
        b[i] = *(const short8*)&cb[(((wc << 6) + (i << 4) + mrow) << 5) + kg];
        a[i] = *(const short8*)&hBuf[((wr << 6) + (i << 4) + mrow) * HSTRIDE + k0 + kg];
      }
      #pragma unroll
      for (int mt = 0; mt < 4; ++mt)
        #pragma unroll
        for (int nti = 0; nti < 4; ++nti)
          acc[mt][nti] = __builtin_amdgcn_mfma_f32_16x16x32_bf16(a[mt], b[nti], acc[mt][nti], 0, 0, 0);
      buf ^= 1;
    }

    #pragma unroll
    for (int nti = 0; nti < 4; ++nti) {
      const int colg = (nt << 7) + (wc << 6) + (nti << 4) + ln;
      const float bs = b_out[colg];
      #pragma unroll
      for (int mt = 0; mt < 4; ++mt) {
        const int rowg = T0 + (wr << 6) + (mt << 4) + lm;
        #pragma unroll
        for (int r = 0; r < 4; ++r)
          out[(size_t)(rowg + r) * NVOCAB + colg] = acc[mt][nti][r] + bs;
      }
    }
  }
}

extern "C" void kernel_launch(void* const* d_in, const int* in_sizes, int n_in,
                              void* d_out, int out_size, void* d_ws, size_t ws_size,
                              hipStream_t stream) {
  const int*   chars      = (const int*)  d_in[0];
  const float* byte_embed = (const float*)d_in[1];
  const float* hash_tabs  = (const float*)d_in[2];
  const float* w_in       = (const float*)d_in[3];
  const float* b_in       = (const float*)d_in[4];
  const float* mlp_ws     = (const float*)d_in[5];
  const float* mlp_bs     = (const float*)d_in[6];
  const float* w_out      = (const float*)d_in[7];
  const float* b_out      = (const float*)d_in[8];

  u16* wInB  = (u16*)d_ws;       // 262144 elems
  u16* wMlpB = wInB  + 262144;   // 786432 elems
  u16* wOutB = wMlpB + 786432;   // 524288 elems

  dim3 blk(256);
  cvt_bf16<<<dim3(256), blk, 0, stream>>>(w_in,   wInB,  262144);
  cvt_bf16<<<dim3(768), blk, 0, stream>>>(mlp_ws, wMlpB, 786432);
  cvt_bf16<<<dim3(512), blk, 0, stream>>>(w_out,  wOutB, 524288);

  constexpr size_t SMEM = (size_t)(128 * HSTRIDE + 2 * 4096) * sizeof(u16); // 149,504 B
  fused_model<<<dim3(512), blk, SMEM, stream>>>(
      chars, byte_embed, hash_tabs, b_in, mlp_bs, b_out,
      wInB, wMlpB, wOutB, (float*)d_out);
}